// Round 1
// 133.231 us; speedup vs baseline: 1.0067x; 1.0067x over previous
//
#include <hip/hip_runtime.h>

#define DIM 4096
using F2 = float2;

// R14 = R13 with the LDS transpose buffer halved to 16 KB (split transposes).
// Rationale: R13 counters show latency-bound (VALUBusy 51%, Occupancy 16.6%,
// HBM 3%, bank conflicts negligible). 32 KB/block capped residency; halving
// LDS doubles resident blocks/CU (grid supplies exactly 8/CU; VGPR 116 allows
// 16 waves/CU). Every layout transition shares one register-index address bit
// between source and dest layouts; with B/C register numbering RELABELED so
// the shared bit is the SAME register bit on both sides, the state splits into
// two closed 2048-amp halves, each transposed through an 11-bit compressed
// address space (shared bit deleted) in one 16 KB buffer — no register copies
// (round h stores and reloads the same 16 registers). Gate math/coefs/prep:
// byte-identical to R13; only masks relabeled.
//
// Layouts (address bit a[11-q] <-> qubit q):
//  A: r = a[11:7]                   qubits {0,1,2,3,4}   masks {16,8,4,2,1}
//  B: a7=r0, a[6:3]=r[4:1]          qubits {4,5,6,7,8}   masks {1,16,8,4,2}
//  C: a11=r0, a3=r1, a[2:0]=r[4:2]  qubits {8,9,10,11,0} masks {2,16,8,4,1}
// Transitions: T1 A->B, T4 B->A share a7 = (r&1) both sides  -> swizzle s1
//              T2 B->C, T3 C->B share a3 = (r&2) both sides  -> swizzle s2
// Compressed addresses (11-bit, shared bit deleted, 2048 F2 = 16 KB):
//  caddrA : [10:7]=r>>1, [6:0]=t                        (T1 store / T4 load)
//  caddrB1: [10:7]=t>>3, [6:3]=r>>1, [2:0]=t&7          (T1 load  / T4 store)
//  caddrB2: [10:7]=t>>3, [6]=r&1, [5:3]=r>>2, [2:0]=t&7 (T2 store / T3 load)
//  caddrC2: [10]=r&1, [9:3]=t, [2:0]=r>>2               (T2 load  / T3 store)
// Bank analysis (b64, 16-entry bank cycle, free 2-way): all 8 patterns give
// 16 distinct (swz(caddr)&15) values x 4 lanes per wave -> conflict-free.

__device__ __forceinline__ int caddrA (int r, int t) { return ((r >> 1) << 7) | t; }
__device__ __forceinline__ int caddrB1(int r, int t) { return ((t >> 3) << 7) | ((r >> 1) << 3) | (t & 7); }
__device__ __forceinline__ int caddrB2(int r, int t) { return ((t >> 3) << 7) | ((r & 1) << 6) | ((r >> 2) << 3) | (t & 7); }
__device__ __forceinline__ int caddrC2(int r, int t) { return ((r & 1) << 10) | (t << 3) | (r >> 2); }
__device__ __forceinline__ int s1(int a) { return a ^ ((a >> 5) & 8); }
__device__ __forceinline__ int s2(int a) { return a ^ ((a >> 4) & 15); }

// ---- packed fp32 complex primitives (VOP3P) — proven R8-R13 ----
__device__ __forceinline__ F2 pk_mul_bl(F2 a, F2 u) {   // (a.x*u.x, a.y*u.x)
    F2 d;
    asm("v_pk_mul_f32 %0, %1, %2 op_sel:[0,0] op_sel_hi:[1,0]"
        : "=v"(d) : "v"(a), "v"(u));
    return d;
}
__device__ __forceinline__ void pk_cross(F2& d, F2 a, F2 u) {  // d += (-a.y*u.y, a.x*u.y)
    asm("v_pk_fma_f32 %0, %1, %2, %0 op_sel:[1,1,0] op_sel_hi:[0,1,1] neg_lo:[1,0,0]"
        : "+v"(d) : "v"(a), "v"(u));
}
__device__ __forceinline__ void pk_fma_bl(F2& d, F2 a, F2 u) { // d += (a.x*u.x, a.y*u.x)
    asm("v_pk_fma_f32 %0, %1, %2, %0 op_sel:[0,0,0] op_sel_hi:[1,0,1]"
        : "+v"(d) : "v"(a), "v"(u));
}
__device__ __forceinline__ void pk_swapneg(F2& d, F2 a, F2 cs) { // d += (a.y*cs.y, -a.x*cs.y)
    asm("v_pk_fma_f32 %0, %1, %2, %0 op_sel:[1,1,0] op_sel_hi:[0,1,1] neg_hi:[1,0,0]"
        : "+v"(d) : "v"(a), "v"(cs));
}
__device__ __forceinline__ void pk_fma(F2& d, F2 a, F2 b) {    // d += a*b
    asm("v_pk_fma_f32 %0, %1, %2, %0" : "+v"(d) : "v"(a), "v"(b));
}
__device__ __forceinline__ void pk_imacc(F2& d, F2 a0, F2 a1) { // d += (a0.x*a1.y, -a0.y*a1.x)
    asm("v_pk_fma_f32 %0, %1, %2, %0 op_sel:[0,1,0] op_sel_hi:[1,0,1] neg_hi:[1,0,0]"
        : "+v"(d) : "v"(a0), "v"(a1));
}
__device__ __forceinline__ F2 pk_cmul(F2 u, F2 a) {
    F2 d = pk_mul_bl(a, u);
    pk_cross(d, a, u);
    return d;
}
__device__ __forceinline__ void pk_cfma(F2& d, F2 u, F2 a) {
    pk_fma_bl(d, a, u);
    pk_cross(d, a, u);
}

__device__ __forceinline__ void build_u(float tx, float ty, float tz, float* u) {
    float sx = sinf(0.5f*tx), cx = cosf(0.5f*tx);
    float sy = sinf(0.5f*ty), cy = cosf(0.5f*ty);
    float sz = sinf(0.5f*tz), cz = cosf(0.5f*tz);
    float A00r = cy*cx, A00i =  sy*sx;     // A = Ry*Rx
    float A01r = -sy*cx, A01i = -cy*sx;
    float A10r =  sy*cx, A10i = -cy*sx;
    float A11r =  cy*cx, A11i = -sy*sx;
    // U = Rz*A: row0 *= (cz - i sz), row1 *= (cz + i sz)   [verified r1/3/5..13]
    u[0] = cz*A00r + sz*A00i;  u[1] = cz*A00i - sz*A00r;
    u[2] = cz*A01r + sz*A01i;  u[3] = cz*A01i - sz*A01r;
    u[4] = cz*A10r - sz*A10i;  u[5] = cz*A10i + sz*A10r;
    u[6] = cz*A11r - sz*A11i;  u[7] = cz*A11i + sz*A11r;
}

// coef layout (floats): [0..95] U0 plain (q*8); [96..191] RX(ang[36+q-1])*U0[q] (q=1..11);
// [192..287] U1 plain; [288..295] U1[0]*RX(ang[47]); [296..319] L1 CRX (cos,sin)[c=0..11]
__global__ void prep_kernel(const float* __restrict__ ang, float* __restrict__ coef) {
    int t = threadIdx.x;
    if (t < 12) {
        float u[8]; build_u(ang[t], ang[12+t], ang[24+t], u);
#pragma unroll
        for (int j = 0; j < 8; ++j) coef[t*8 + j] = u[j];
    } else if (t < 24) {
        int q = t - 12;
        float u[8]; build_u(ang[48+q], ang[60+q], ang[72+q], u);
#pragma unroll
        for (int j = 0; j < 8; ++j) coef[192 + q*8 + j] = u[j];
    } else if (t < 36) {
        int c = t - 24;
        float th = 0.5f * ang[95 - c];     // L1 ring gate (c,c+1) = tape slot 84+(11-c)
        coef[296 + c*2]     = cosf(th);
        coef[296 + c*2 + 1] = sinf(th);
    } else if (t < 47) {
        int q = t - 35;                    // 1..11: M = RX(ang[36+q-1]) * U0[q]
        float u[8]; build_u(ang[q], ang[12+q], ang[24+q], u);
        float c = cosf(0.5f*ang[36+q-1]), s = sinf(0.5f*ang[36+q-1]);
        float m[8];
        m[0] = c*u[0] + s*u[5];  m[1] = c*u[1] - s*u[4];   // M00 = c u00 - i s u10
        m[2] = c*u[2] + s*u[7];  m[3] = c*u[3] - s*u[6];   // M01 = c u01 - i s u11
        m[4] = s*u[1] + c*u[4];  m[5] = -s*u[0] + c*u[5];  // M10 = -i s u00 + c u10
        m[6] = s*u[3] + c*u[6];  m[7] = -s*u[2] + c*u[7];  // M11 = -i s u01 + c u11
#pragma unroll
        for (int j = 0; j < 8; ++j) coef[96 + q*8 + j] = m[j];
    } else if (t == 47) {                  // M = U1[0] * RX(ang[47])  [CR0(11,0) then U1(0)]
        float u[8]; build_u(ang[48], ang[60], ang[72], u);
        float c = cosf(0.5f*ang[47]), s = sinf(0.5f*ang[47]);
        float m[8];
        m[0] = c*u[0] + s*u[3];  m[1] = c*u[1] - s*u[2];   // M00 = c u00 - i s u01
        m[2] = s*u[1] + c*u[2];  m[3] = -s*u[0] + c*u[3];  // M01 = -i s u00 + c u01
        m[4] = c*u[4] + s*u[7];  m[5] = c*u[5] - s*u[6];   // M10 = c u10 - i s u11
        m[6] = s*u[5] + c*u[6];  m[7] = -s*u[4] + c*u[7];  // M11 = -i s u10 + c u11
#pragma unroll
        for (int j = 0; j < 8; ++j) coef[288 + j] = m[j];
    }
}

// SB != 0 restricts processing to pairs with (r0 & SB) == HB (half-gates that
// fill the split-transpose store windows). SB is never equal to M.
template<int M, int SB, int HB>
__device__ __forceinline__ void g1q(F2* amp, const float* __restrict__ u) {
    F2 u00 = {u[0], u[1]}, u01 = {u[2], u[3]};
    F2 u10 = {u[4], u[5]}, u11 = {u[6], u[7]};
#pragma unroll
    for (int r0 = 0; r0 < 32; ++r0) {
        if (r0 & M) continue;
        if (SB != 0 && (r0 & SB) != HB) continue;
        const int r1 = r0 + M;
        F2 a0 = amp[r0], a1 = amp[r1];
        F2 n0 = pk_cmul(u00, a0); pk_cfma(n0, u01, a1);
        F2 n1 = pk_cmul(u10, a0); pk_cfma(n1, u11, a1);
        amp[r0] = n0; amp[r1] = n1;
    }
}

template<int MSEL, int M, int SB, int HB>   // matrix selected by control bit MSEL
__device__ __forceinline__ void fg1q(F2* amp, const float* __restrict__ uA,
                                     const float* __restrict__ uB) {
    F2 a00 = {uA[0], uA[1]}, a01 = {uA[2], uA[3]}, a10 = {uA[4], uA[5]}, a11 = {uA[6], uA[7]};
    F2 b00 = {uB[0], uB[1]}, b01 = {uB[2], uB[3]}, b10 = {uB[4], uB[5]}, b11 = {uB[6], uB[7]};
#pragma unroll
    for (int r0 = 0; r0 < 32; ++r0) {
        if (r0 & M) continue;
        if (SB != 0 && (r0 & SB) != HB) continue;
        const int r1 = r0 + M;
        const bool sel = (r0 & MSEL) != 0;           // compile-time
        F2 u00 = sel ? b00 : a00, u01 = sel ? b01 : a01;
        F2 u10 = sel ? b10 : a10, u11 = sel ? b11 : a11;
        F2 a0 = amp[r0], a1 = amp[r1];
        F2 n0 = pk_cmul(u00, a0); pk_cfma(n0, u01, a1);
        F2 n1 = pk_cmul(u10, a0); pk_cfma(n1, u11, a1);
        amp[r0] = n0; amp[r1] = n1;
    }
}

template<int MC, int MT>
__device__ __forceinline__ void crx(F2* amp, F2 cs) {
#pragma unroll
    for (int r0 = 0; r0 < 32; ++r0) {
        if (!(r0 & MC) || (r0 & MT)) continue;
        const int r1 = r0 + MT;
        F2 a0 = amp[r0], a1 = amp[r1];
        F2 n0 = pk_mul_bl(a0, cs); pk_swapneg(n0, a1, cs);
        F2 n1 = pk_mul_bl(a1, cs); pk_swapneg(n1, a0, cs);
        amp[r0] = n0; amp[r1] = n1;
    }
}

template<int M>
__device__ __forceinline__ void expv(const F2* amp, int q, int lane,
                                     float& fx, float& fy, float& fz) {
    F2 zp = {0.f, 0.f}, zm = {0.f, 0.f}, xp = {0.f, 0.f}, ip = {0.f, 0.f};
#pragma unroll
    for (int r0 = 0; r0 < 32; ++r0) {
        if (r0 & M) continue;
        const int r1 = r0 + M;
        F2 a0 = amp[r0], a1 = amp[r1];
        pk_fma(zp, a0, a0);
        pk_fma(zm, a1, a1);
        pk_fma(xp, a0, a1);
        pk_imacc(ip, a0, a1);
    }
    float zz = (zp.x + zp.y) - (zm.x + zm.y);
    float xr = 2.f * (xp.x + xp.y);
    float xi = 2.f * (ip.x + ip.y);
#pragma unroll
    for (int off = 32; off; off >>= 1) {
        xr += __shfl_xor(xr, off);
        xi += __shfl_xor(xi, off);
        zz += __shfl_xor(zz, off);
    }
    if (lane == q) { fx = xr; fy = xi; fz = zz; }
}

// enumerate j-th pair base r0 with (r0 & M)==0 and (r0 & SB)==hb*SB
template<int M, int SB>
__device__ __forceinline__ int r0_of(int j, int hb) {
    int r = hb ? SB : 0, b = 1;
#pragma unroll
    for (int p = 0; p < 5; ++p) {
        const int mm = 1 << p;
        if (mm == M || mm == SB) continue;
        if (j & b) r |= mm;
        b <<= 1;
    }
    return r;
}

// Store one half (16 regs with (r & SB) == HB); order irrelevant for drain.
#define ST_H(CADDR, SWZ, SB, HB) \
  { _Pragma("unroll") for (int r = 0; r < 32; ++r) { \
      if ((r & (SB)) != (HB)) continue; \
      psi[SWZ(CADDR(r, t))] = amp[r]; } }
// Load one half in pair order of the next gate (mask M): pairs (r0, r0+M)
// issue adjacently so the first gate starts after 2 loads.
#define LD_H(CADDR, SWZ, M, SB, HB) \
  { _Pragma("unroll") for (int k = 0; k < 16; ++k) { \
      const int j = k >> 1; \
      const int r0 = r0_of<M, SB>(j, (HB) != 0); \
      const int r = (k & 1) ? (r0 + (M)) : r0; \
      amp[r] = psi[SWZ(CADDR(r, t))]; } }

#define U0P(q, M)               g1q<M, 0, 0>(amp, cf + (q)*8)
#define FU0(q, MS, M)           fg1q<MS, M, 0, 0>(amp, cf + (q)*8, cf + 96 + (q)*8)
#define FU0_H(q, MS, M, SB, HB) fg1q<MS, M, SB, HB>(amp, cf + (q)*8, cf + 96 + (q)*8)
#define U1P(q, M)               g1q<M, 0, 0>(amp, cf + 192 + (q)*8)
#define U1P_H(q, M, SB, HB)     g1q<M, SB, HB>(amp, cf + 192 + (q)*8)
#define FU1_0()                 fg1q<4, 1, 0, 0>(amp, cf + 192, cf + 288)
#define CR1(c, MC, MT)          crx<MC, MT>(amp, F2{cf[296 + (c)*2], cf[296 + (c)*2 + 1]})
#define EXPV(q, M)              expv<M>(amp, q, lane, fx, fy, fz)

__global__ __launch_bounds__(128, 1)
void qsim_kernel(const float* __restrict__ sv,      // [B, 4096]
                 const float* __restrict__ cf,      // [320] precomputed coefficients
                 const float* __restrict__ W,       // [10, 36]
                 const float* __restrict__ bvec,    // [10]
                 float* __restrict__ out)           // [B, 10]
{
    __shared__ F2 psi[2048];         // 16 KB (was 32 KB) -> 2x resident blocks
    const int t = threadIdx.x;
    const int b = blockIdx.x;
    const int lane = t & 63, w = t >> 6;

    F2 amp[32];
    const float* svb = sv + (size_t)b * DIM;
#pragma unroll
    for (int r = 0; r < 32; ++r)                    // layout A, coalesced
        amp[r] = make_float2(svb[(r << 7) | t], 0.f);

    float fx = 0.f, fy = 0.f, fz = 0.f;

    // ---- A {0,1,2,3,4} masks {16,8,4,2,1}: U0(0); [U0(q);CR0(q-1,q)] q=1..4 ----
    U0P(0, 16);
    FU0(1, 16, 8); FU0(2, 8, 4); FU0(3, 4, 2); FU0(4, 2, 1);

    // ---- T1: A->B, split bit r&1 (=a7 both sides), swizzle s1 ----
    ST_H(caddrA, s1, 1, 0);
    __syncthreads();
    LD_H(caddrB1, s1, 16, 1, 0);     // first B gate FU0(5,1,16): pairs on mask 16
    __syncthreads();
    ST_H(caddrA, s1, 1, 1);
    FU0_H(5, 1, 16, 1, 0);           // half-gate on loaded (even) regs fills window
    __syncthreads();
    LD_H(caddrB1, s1, 16, 1, 1);
    FU0_H(5, 1, 16, 1, 1);

    // ---- B {4,5,6,7,8} masks {1,16,8,4,2}: [U0(q);CR0(q-1,q)] q=6..8 ----
    FU0(6, 16, 8); FU0(7, 8, 4); FU0(8, 4, 2);

    // ---- T2: B->C, split bit r&2 (=a3 both sides), swizzle s2 ----
    __syncthreads();                 // protect T1-h1 loads before buffer reuse
    ST_H(caddrB2, s2, 2, 0);
    __syncthreads();
    LD_H(caddrC2, s2, 16, 2, 0);     // first C gate FU0(9,2,16): pairs on mask 16
    __syncthreads();
    ST_H(caddrB2, s2, 2, 2);
    FU0_H(9, 2, 16, 2, 0);
    __syncthreads();
    LD_H(caddrC2, s2, 16, 2, 2);
    FU0_H(9, 2, 16, 2, 2);

    // ---- C {8,9,10,11,0} masks {2,16,8,4,1}: q=10,11; [CR0(11,0);U1(0)];
    //      U1(8..11); L1 ring (11,0),(10,11),(9,10),(8,9) ----
    FU0(10, 16, 8); FU0(11, 8, 4);
    FU1_0();
    U1P(8, 2); U1P(9, 16); U1P(10, 8); U1P(11, 4);
    CR1(11, 4, 1); CR1(10, 8, 4); CR1(9, 16, 8); CR1(8, 2, 16);

    // ---- T3: C->B', split bit r&2, swizzle s2 ----
    __syncthreads();
    ST_H(caddrC2, s2, 2, 0);
    EXPV(9, 16); EXPV(10, 8); EXPV(11, 4);   // reads amp only — fills store drain
    __syncthreads();
    LD_H(caddrB2, s2, 1, 2, 0);      // first B' gate U1P(4,1): pairs on mask 1
    __syncthreads();
    ST_H(caddrC2, s2, 2, 2);
    U1P_H(4, 1, 2, 0);
    __syncthreads();
    LD_H(caddrB2, s2, 1, 2, 2);
    U1P_H(4, 1, 2, 2);

    // ---- B' {4,5,6,7,8}: U1(5..7); L1 ring (7,8),(6,7),(5,6),(4,5) ----
    U1P(5, 16); U1P(6, 8); U1P(7, 4);
    CR1(7, 4, 2); CR1(6, 8, 4); CR1(5, 16, 8); CR1(4, 1, 16);

    // ---- T4: B'->A', split bit r&1, swizzle s1 ----
    __syncthreads();
    ST_H(caddrB1, s1, 1, 0);
    EXPV(5, 16); EXPV(6, 8); EXPV(7, 4); EXPV(8, 2);   // fills store drain
    __syncthreads();
    LD_H(caddrA, s1, 8, 1, 0);       // first A' gate U1P(1,8): pairs on mask 8
    __syncthreads();
    ST_H(caddrB1, s1, 1, 1);
    U1P_H(1, 8, 1, 0);
    __syncthreads();
    LD_H(caddrA, s1, 8, 1, 1);
    U1P_H(1, 8, 1, 1);

    // ---- A' {0,1,2,3,4}: U1(2,3); L1 ring (3,4),(2,3),(1,2),(0,1); expv 0..4 ----
    U1P(2, 4); U1P(3, 2);
    CR1(3, 2, 1); CR1(2, 4, 2); CR1(1, 8, 4); CR1(0, 16, 8);
    EXPV(0, 16); EXPV(1, 8); EXPV(2, 4); EXPV(3, 2); EXPV(4, 1);

    // ---- combine 2 waves' features (psi dead after T4-h1 loads drain: alias) ----
    __syncthreads();
    float* fbuf = (float*)psi;       // [2][36]
    if (lane < 12) {
        fbuf[w * 36 + lane]      = fx;
        fbuf[w * 36 + 12 + lane] = fy;
        fbuf[w * 36 + 24 + lane] = fz;
    }
    __syncthreads();
    if (t < 10) {
        float a = bvec[t];
#pragma unroll
        for (int f = 0; f < 36; ++f)
            a += W[t * 36 + f] * (fbuf[f] + fbuf[36 + f]);
        out[(size_t)b * 10 + t] = a;
    }
}

extern "C" void kernel_launch(void* const* d_in, const int* in_sizes, int n_in,
                              void* d_out, int out_size, void* d_ws, size_t ws_size,
                              hipStream_t stream) {
    const float* sv     = (const float*)d_in[0];
    const float* angles = (const float*)d_in[1];
    const float* W      = (const float*)d_in[2];
    const float* bvec   = (const float*)d_in[3];
    float* out  = (float*)d_out;
    float* coef = (float*)d_ws;      // 320 floats of scratch
    int batch = in_sizes[0] / DIM;   // 2048
    prep_kernel<<<1, 64, 0, stream>>>(angles, coef);
    qsim_kernel<<<batch, 128, 0, stream>>>(sv, coef, W, bvec, out);
}